// Round 2
// baseline (257.934 us; speedup 1.0000x reference)
//
#include <hip/hip_runtime.h>
#include <hip/hip_bf16.h>

#define N_ROWS 300000
#define FIN    128
#define HDIM   64
#define ODIM   32
#define KREL   5
#define BR     128
#define NTILES ((N_ROWS + BR - 1) / BR + KREL)   // 2349 max
#define NB     (NTILES * BR)
#define GBLK   512

typedef __attribute__((ext_vector_type(8))) short bf8_t;   // 8 bf16 = 4 VGPR
typedef __attribute__((ext_vector_type(4))) float f32x4;
typedef __attribute__((ext_vector_type(4))) unsigned int u32x4;

static __device__ __forceinline__ unsigned short f2bf(float f) {
  unsigned int u = __float_as_uint(f);
  return (unsigned short)((u + 0x7FFFu + ((u >> 16) & 1u)) >> 16);   // RNE
}

static __device__ __forceinline__ unsigned pk2(float lo, float hi) {
  __hip_bfloat162 h = __float22bfloat162_rn(make_float2(lo, hi));
  return *reinterpret_cast<unsigned*>(&h);
}

static __device__ __forceinline__ bf8_t cvt8(float4 a, float4 b) {
  u32x4 u;
  u.x = pk2(a.x, a.y);
  u.y = pk2(a.z, a.w);
  u.z = pk2(b.x, b.y);
  u.w = pk2(b.z, b.w);
  return __builtin_bit_cast(bf8_t, u);
}

static __device__ __forceinline__ bf8_t lds_load16(const void* base, int byte) {
  return *(const bf8_t*)((const char*)base + byte);
}

static __device__ __forceinline__ void stbf4(void* base, int byte, float4 v) {
  unsigned long long p = (unsigned long long)f2bf(v.x)
                       | ((unsigned long long)f2bf(v.y) << 16)
                       | ((unsigned long long)f2bf(v.z) << 32)
                       | ((unsigned long long)f2bf(v.w) << 48);
  *(unsigned long long*)((char*)base + byte) = p;
}

// ---------------- bucketing ----------------

__global__ void hist_kernel(const int* __restrict__ r, int* __restrict__ cnt) {
  __shared__ int lc[KREL];
  int tid = threadIdx.x;
  if (tid < KREL) lc[tid] = 0;
  __syncthreads();
  int i = blockIdx.x * blockDim.x + tid;
  if (i < N_ROWS) atomicAdd(&lc[r[i]], 1);
  __syncthreads();
  if (tid < KREL && lc[tid]) atomicAdd(&cnt[tid], lc[tid]);
}

__global__ void offs_kernel(const int* __restrict__ cnt, int* __restrict__ aoff,
                            int* __restrict__ cursor) {
  int off = 0;
  for (int k = 0; k < KREL; ++k) {
    aoff[k] = off;
    cursor[k] = off;
    off += ((cnt[k] + BR - 1) / BR) * BR;
  }
  aoff[KREL] = off;
}

__global__ void scat_kernel(const int* __restrict__ r, int* __restrict__ bucket,
                            int* __restrict__ cursor) {
  __shared__ int lc[KREL];
  __shared__ int base[KREL];
  int tid = threadIdx.x;
  if (tid < KREL) lc[tid] = 0;
  __syncthreads();
  int i = blockIdx.x * blockDim.x + tid;
  int k = 0, lr = 0;
  if (i < N_ROWS) { k = r[i]; lr = atomicAdd(&lc[k], 1); }
  __syncthreads();
  if (tid < KREL) base[tid] = lc[tid] ? atomicAdd(&cursor[tid], lc[tid]) : 0;
  __syncthreads();
  if (i < N_ROWS) bucket[base[k] + lr] = i;
}

// ---------------- main fused kernel ----------------
// 512 threads = 8 waves; each wave owns 16 rows of a 128-row tile.
// No X LDS staging: A-fragments gathered straight from global.
// Per-wave private H scratch -> no barriers in the steady-state tile loop.

__global__ __launch_bounds__(512, 4) void gcn_main(
    const float* __restrict__ user, const float* __restrict__ item,
    const float* __restrict__ c,
    const float* __restrict__ Wu, const float* __restrict__ bu,
    const float* __restrict__ Wv, const float* __restrict__ bv,
    const float* __restrict__ Wl, const float* __restrict__ bl,
    const int* __restrict__ bucket, const int* __restrict__ aoff,
    float* __restrict__ out)
{
  __shared__ __align__(16) unsigned short sWu[HDIM * FIN];   // 16 KB bf16, swizzled
  __shared__ __align__(16) unsigned short sWv[HDIM * FIN];
  __shared__ __align__(16) unsigned short sH[8 * 2048];      // 4 KB per wave

  const int tid  = threadIdx.x;
  const int lane = tid & 63;
  const int wid  = tid >> 6;
  const int lrow = lane & 15;
  const int lkg  = lane >> 4;

  const int total = aoff[KREL];
  const int NT    = total / BR;
  const int a1 = aoff[1], a2 = aoff[2], a3 = aoff[3], a4 = aoff[4];

  int t0 = (int)(((long long)blockIdx.x * NT) / GBLK);
  int t1 = (int)(((long long)(blockIdx.x + 1) * NT) / GBLK);
  if (t0 >= t1) return;

  // layer-2 weight fragments (Wl[32][64]) + bias, in registers for good
  bf8_t wl[2][2];
  #pragma unroll
  for (int n2 = 0; n2 < 2; ++n2)
    #pragma unroll
    for (int k2 = 0; k2 < 2; ++k2) {
      const float* p = Wl + (size_t)(n2 * 16 + lrow) * HDIM + k2 * 32 + lkg * 8;
      float4 x0 = *(const float4*)p;
      float4 x1 = *(const float4*)(p + 4);
      wl[n2][k2] = cvt8(x0, x1);
    }
  const float blv0 = bl[lrow];
  const float blv1 = bl[16 + lrow];

  unsigned short* myH = sH + wid * 2048;     // 4096 bytes: [side(2)][row(16)][col(64)] bf16

  int   cur_rel = -1;
  float bU[4], bV[4];

  for (int t = t0; t < t1; ++t) {
    const int tile0 = t * BR;
    int rel = (tile0 >= a1) + (tile0 >= a2) + (tile0 >= a3) + (tile0 >= a4);

    if (rel != cur_rel) {               // rare: <= 2 per block (tiles sorted by rel)
      __syncthreads();
      const float4* wu4 = (const float4*)(Wu + (size_t)rel * HDIM * FIN);
      const float4* wv4 = (const float4*)(Wv + (size_t)rel * HDIM * FIN);
      #pragma unroll
      for (int it = 0; it < 4; ++it) {
        int f4  = it * 512 + tid;        // 0..2047
        int row = f4 >> 5;               // 32 float4 per 128-col row
        int c4  = f4 & 31;
        int byte = (row * 256 + c4 * 8) ^ ((row & 7) << 4);
        stbf4(sWu, byte, wu4[f4]);
        stbf4(sWv, byte, wv4[f4]);
      }
      #pragma unroll
      for (int n = 0; n < 4; ++n) {
        bU[n] = bu[rel * HDIM + n * 16 + lrow];
        bV[n] = bv[rel * HDIM + n * 16 + lrow];
      }
      cur_rel = rel;
      __syncthreads();
    }

    // row indices: A-rows (for X gather) and C-rows (for c, out)
    const int rowbase = tile0 + wid * 16;
    const int idxA = bucket[rowbase + lrow];
    int   idxQ[4];
    float cQ[4];
    #pragma unroll
    for (int q = 0; q < 4; ++q) {
      int iq = bucket[rowbase + lkg * 4 + q];
      idxQ[q] = iq;
      float cv = c[iq < 0 ? 0 : iq];
      cQ[q] = (iq < 0) ? 0.0f : cv;
    }

    // ---- layer 1: A direct-from-global, B from LDS weights ----
    f32x4 accU[4], accV[4];
    #pragma unroll
    for (int n = 0; n < 4; ++n) {
      accU[n] = f32x4{0.f, 0.f, 0.f, 0.f};
      accV[n] = f32x4{0.f, 0.f, 0.f, 0.f};
    }

    const bool va = (idxA >= 0);
    const size_t xoff = (size_t)(va ? idxA : 0) * FIN + lkg * 8;
    const float* pu = item + xoff;
    const float* pv = user + xoff;
    const float4 z4 = make_float4(0.f, 0.f, 0.f, 0.f);

    #pragma unroll
    for (int kc = 0; kc < 4; ++kc) {
      float4 a0 = va ? *(const float4*)(pu + kc * 32)     : z4;
      float4 a1v= va ? *(const float4*)(pu + kc * 32 + 4) : z4;
      float4 b0 = va ? *(const float4*)(pv + kc * 32)     : z4;
      float4 b1 = va ? *(const float4*)(pv + kc * 32 + 4) : z4;
      bf8_t au = cvt8(a0, a1v);
      bf8_t av = cvt8(b0, b1);
      const int kb = (kc * 32 + lkg * 8) * 2;
      #pragma unroll
      for (int n = 0; n < 4; ++n) {
        int brow = n * 16 + lrow;
        int bx   = (brow * 256 + kb) ^ ((brow & 7) << 4);
        accU[n] = __builtin_amdgcn_mfma_f32_16x16x32_bf16(au, lds_load16(sWu, bx), accU[n], 0, 0, 0);
        accV[n] = __builtin_amdgcn_mfma_f32_16x16x32_bf16(av, lds_load16(sWv, bx), accV[n], 0, 0, 0);
      }
    }

    // epilogue 1: H = relu(c*(acc+b)) -> per-wave LDS [2][16][64] bf16, swizzled
    #pragma unroll
    for (int n = 0; n < 4; ++n) {
      int hcol = n * 16 + lrow;
      #pragma unroll
      for (int q = 0; q < 4; ++q) {
        int rr   = lkg * 4 + q;
        int byte = (rr * 128 + hcol * 2) ^ ((rr & 7) << 4);
        float hu = fmaxf(cQ[q] * (accU[n][q] + bU[n]), 0.f);
        float hv = fmaxf(cQ[q] * (accV[n][q] + bV[n]), 0.f);
        *(unsigned short*)((char*)myH + byte)        = f2bf(hu);
        *(unsigned short*)((char*)myH + 2048 + byte) = f2bf(hv);
      }
    }
    // same-wave LDS RAW: compiler inserts lgkmcnt wait; no barrier needed.

    // ---- layer 2: [16 rows] x [32 o], K = 64 ----
    f32x4 accOU[2], accOV[2];
    #pragma unroll
    for (int n2 = 0; n2 < 2; ++n2) {
      accOU[n2] = f32x4{0.f, 0.f, 0.f, 0.f};
      accOV[n2] = f32x4{0.f, 0.f, 0.f, 0.f};
    }
    #pragma unroll
    for (int k2 = 0; k2 < 2; ++k2) {
      const int kb = (k2 * 32 + lkg * 8) * 2;
      const int ax = (lrow * 128 + kb) ^ ((lrow & 7) << 4);
      bf8_t a2u = lds_load16(myH, ax);
      bf8_t a2v = lds_load16((const char*)myH + 2048, ax);
      #pragma unroll
      for (int n2 = 0; n2 < 2; ++n2) {
        accOU[n2] = __builtin_amdgcn_mfma_f32_16x16x32_bf16(a2u, wl[n2][k2], accOU[n2], 0, 0, 0);
        accOV[n2] = __builtin_amdgcn_mfma_f32_16x16x32_bf16(a2v, wl[n2][k2], accOV[n2], 0, 0, 0);
      }
    }

    // epilogue 2: out = relu(acc + bl), scattered row stores
    #pragma unroll
    for (int n2 = 0; n2 < 2; ++n2) {
      int col  = n2 * 16 + lrow;
      float bb = (n2 == 0) ? blv0 : blv1;
      #pragma unroll
      for (int q = 0; q < 4; ++q) {
        int idx = idxQ[q];
        if (idx >= 0) {
          out[(size_t)idx * ODIM + col]            = fmaxf(accOU[n2][q] + bb, 0.f);
          out[(size_t)(N_ROWS + idx) * ODIM + col] = fmaxf(accOV[n2][q] + bb, 0.f);
        }
      }
    }
  }
}

extern "C" void kernel_launch(void* const* d_in, const int* in_sizes, int n_in,
                              void* d_out, int out_size, void* d_ws, size_t ws_size,
                              hipStream_t stream) {
  const float* user = (const float*)d_in[0];
  const float* item = (const float*)d_in[1];
  const int*   r    = (const int*)d_in[2];
  const float* c    = (const float*)d_in[3];
  const float* Wu   = (const float*)d_in[4];
  const float* bu   = (const float*)d_in[5];
  const float* Wv   = (const float*)d_in[6];
  const float* bv   = (const float*)d_in[7];
  const float* Wl   = (const float*)d_in[8];
  const float* bl   = (const float*)d_in[9];
  float* out = (float*)d_out;

  int* bucket = (int*)d_ws;          // NB ints
  int* cnt    = bucket + NB;         // KREL
  int* cursor = cnt + KREL;          // KREL
  int* aoff   = cursor + KREL;       // KREL+1

  hipMemsetAsync(bucket, 0xFF, (size_t)NB * sizeof(int), stream);
  hipMemsetAsync(cnt, 0, KREL * sizeof(int), stream);

  const int nthr = 256;
  hist_kernel<<<(N_ROWS + nthr - 1) / nthr, nthr, 0, stream>>>(r, cnt);
  offs_kernel<<<1, 1, 0, stream>>>(cnt, aoff, cursor);
  scat_kernel<<<(N_ROWS + nthr - 1) / nthr, nthr, 0, stream>>>(r, bucket, cursor);
  gcn_main<<<GBLK, 512, 0, stream>>>(user, item, c, Wu, bu, Wv, bv, Wl, bl,
                                     bucket, aoff, out);
}

// Round 3
// 163.722 us; speedup vs baseline: 1.5754x; 1.5754x over previous
//
#include <hip/hip_runtime.h>
#include <hip/hip_bf16.h>

#define N_ROWS 300000
#define FIN    128
#define HDIM   64
#define ODIM   32
#define KREL   5
#define BR     64
#define NTILES ((N_ROWS + BR - 1) / BR + KREL)   // 4693
#define NB     (NTILES * BR)

typedef __attribute__((ext_vector_type(8))) short bf8_t;   // 8 bf16 = 4 VGPR
typedef __attribute__((ext_vector_type(4))) float f32x4;
typedef __attribute__((ext_vector_type(4))) unsigned int u32x4;

static __device__ __forceinline__ unsigned pk2(float lo, float hi) {
  __hip_bfloat162 h = __float22bfloat162_rn(make_float2(lo, hi));
  return *reinterpret_cast<unsigned*>(&h);
}

static __device__ __forceinline__ bf8_t cvt8(float4 a, float4 b) {
  u32x4 u;
  u.x = pk2(a.x, a.y);
  u.y = pk2(a.z, a.w);
  u.z = pk2(b.x, b.y);
  u.w = pk2(b.z, b.w);
  return __builtin_bit_cast(bf8_t, u);
}

static __device__ __forceinline__ void stbf4_pk(void* base, int byte, float4 v) {
  unsigned long long p = (unsigned long long)pk2(v.x, v.y)
                       | ((unsigned long long)pk2(v.z, v.w) << 32);
  *(unsigned long long*)((char*)base + byte) = p;
}

static __device__ __forceinline__ bf8_t lds_load16(const void* base, int byte) {
  return *(const bf8_t*)((const char*)base + byte);
}

// ---------------- bucketing ----------------

__global__ void hist_kernel(const int* __restrict__ r, int* __restrict__ cnt) {
  __shared__ int lc[KREL];
  int tid = threadIdx.x;
  if (tid < KREL) lc[tid] = 0;
  __syncthreads();
  int i = blockIdx.x * blockDim.x + tid;
  if (i < N_ROWS) atomicAdd(&lc[r[i]], 1);
  __syncthreads();
  if (tid < KREL && lc[tid]) atomicAdd(&cnt[tid], lc[tid]);
}

__global__ void offs_kernel(const int* __restrict__ cnt, int* __restrict__ aoff,
                            int* __restrict__ cursor) {
  int off = 0;
  for (int k = 0; k < KREL; ++k) {
    aoff[k] = off;
    cursor[k] = off;
    off += ((cnt[k] + BR - 1) / BR) * BR;
  }
  aoff[KREL] = off;
}

__global__ void scat_kernel(const int* __restrict__ r, int* __restrict__ bucket,
                            int* __restrict__ cursor) {
  __shared__ int lc[KREL];
  __shared__ int base[KREL];
  int tid = threadIdx.x;
  if (tid < KREL) lc[tid] = 0;
  __syncthreads();
  int i = blockIdx.x * blockDim.x + tid;
  int k = 0, lr = 0;
  if (i < N_ROWS) { k = r[i]; lr = atomicAdd(&lc[k], 1); }
  __syncthreads();
  if (tid < KREL) base[tid] = lc[tid] ? atomicAdd(&cursor[tid], lc[tid]) : 0;
  __syncthreads();
  if (i < N_ROWS) bucket[base[k] + lr] = i;
}

// ---------------- main fused kernel ----------------
// One block = one 64-row tile x ONE side (U or V). 256 threads = 4 waves,
// each wave owns 16 rows. LDS: W 16KB + X 16KB -> 4 blocks/CU.

__global__ __launch_bounds__(256, 4) void gcn_main(
    const float* __restrict__ user, const float* __restrict__ item,
    const float* __restrict__ c,
    const float* __restrict__ Wu, const float* __restrict__ bu,
    const float* __restrict__ Wv, const float* __restrict__ bv,
    const float* __restrict__ Wl, const float* __restrict__ bl,
    const int* __restrict__ bucket, const int* __restrict__ aoff,
    float* __restrict__ out)
{
  __shared__ __align__(16) unsigned short sW[HDIM * FIN];   // 16 KB bf16, swizzled
  __shared__ __align__(16) unsigned short sX[BR * FIN];     // 16 KB bf16, swizzled (reused as H)
  __shared__ float sC[BR];
  __shared__ int   sIdx[BR];

  const int tid   = threadIdx.x;
  const int side  = blockIdx.x & 1;                 // 0: item->u_out, 1: user->v_out
  const int tile0 = (blockIdx.x >> 1) * BR;
  if (tile0 >= aoff[KREL]) return;

  const float* X  = side ? user : item;
  const float* Wk = side ? Wv : Wu;
  const float* bk = side ? bv : bu;

  int rel = (tile0 >= aoff[1]) + (tile0 >= aoff[2]) + (tile0 >= aoff[3]) + (tile0 >= aoff[4]);

  // stage row indices / c
  if (tid < BR) {
    int idx = bucket[tile0 + tid];
    sIdx[tid] = idx;
    sC[tid]   = (idx >= 0) ? c[idx] : 0.0f;
  }

  // stage relation weights (independent of sIdx) -> bf16 LDS, XOR-swizzled
  const float4* w4 = (const float4*)(Wk + (size_t)rel * HDIM * FIN);
  #pragma unroll
  for (int it = 0; it < 8; ++it) {
    int f4  = it * 256 + tid;        // 0..2047
    int row = f4 >> 5;               // 32 float4 per 128-col row
    int c4  = f4 & 31;
    int byte = (row * 256 + c4 * 8) ^ ((row & 7) << 4);
    stbf4_pk(sW, byte, w4[f4]);
  }

  const int lane = tid & 63;
  const int wid  = tid >> 6;        // wave 0..3, owns rows [wid*16, wid*16+16)
  const int lrow = lane & 15;
  const int lkg  = lane >> 4;

  // per-lane constants (L1/L2-resident, issued before the barrier)
  bf8_t wl[2][2];
  #pragma unroll
  for (int n2 = 0; n2 < 2; ++n2)
    #pragma unroll
    for (int k2 = 0; k2 < 2; ++k2) {
      const float* p = Wl + (size_t)(n2 * 16 + lrow) * HDIM + k2 * 32 + lkg * 8;
      wl[n2][k2] = cvt8(*(const float4*)p, *(const float4*)(p + 4));
    }
  const float blv0 = bl[lrow];
  const float blv1 = bl[16 + lrow];
  float bfrag[4];
  #pragma unroll
  for (int n = 0; n < 4; ++n) bfrag[n] = bk[rel * HDIM + n * 16 + lrow];

  __syncthreads();   // sIdx ready

  // stage gathered X rows -> bf16 LDS (same swizzle)
  #pragma unroll
  for (int it = 0; it < 8; ++it) {
    int f4  = it * 256 + tid;
    int row = f4 >> 5;
    int c4  = f4 & 31;
    int idx = sIdx[row];
    float4 a = make_float4(0.f, 0.f, 0.f, 0.f);
    if (idx >= 0) a = *(const float4*)(X + (size_t)idx * FIN + c4 * 4);
    int byte = (row * 256 + c4 * 8) ^ ((row & 7) << 4);
    stbf4_pk(sX, byte, a);
  }
  __syncthreads();

  // ---- layer 1: [64 rows] x [64 h], K = 128 ----
  f32x4 acc[4];
  #pragma unroll
  for (int n = 0; n < 4; ++n) acc[n] = f32x4{0.f, 0.f, 0.f, 0.f};

  const int arow = wid * 16 + lrow;
  const int axor = (arow & 7) << 4;
  #pragma unroll
  for (int kc = 0; kc < 4; ++kc) {
    const int kb = (kc * 32 + lkg * 8) * 2;   // byte offset within 256 B row
    bf8_t au = lds_load16(sX, (arow * 256 + kb) ^ axor);
    #pragma unroll
    for (int n = 0; n < 4; ++n) {
      int brow = n * 16 + lrow;
      int bx   = (brow * 256 + kb) ^ ((brow & 7) << 4);
      acc[n] = __builtin_amdgcn_mfma_f32_16x16x32_bf16(au, lds_load16(sW, bx), acc[n], 0, 0, 0);
    }
  }

  // epilogue 1: H = relu(c*(acc+b)) -> bf16, stored into THIS WAVE'S own X rows
  // (rows [wid*16, wid*16+16) are read only by this wave; same-wave LDS ordering
  // makes this safe without a barrier). H row stride 128 B, swizzled.
  char* myH = (char*)sX + wid * 4096;
  int   idxQ[4];
  float cQ[4];
  #pragma unroll
  for (int q = 0; q < 4; ++q) {
    int rr = wid * 16 + lkg * 4 + q;
    idxQ[q] = sIdx[rr];
    cQ[q]   = sC[rr];
  }
  #pragma unroll
  for (int n = 0; n < 4; ++n) {
    int hcol = n * 16 + lrow;
    #pragma unroll
    for (int q = 0; q < 4; ++q) {
      int rr   = lkg * 4 + q;      // local row 0..15
      int byte = (rr * 128 + hcol * 2) ^ ((rr & 7) << 4);
      float hv = fmaxf(cQ[q] * (acc[n][q] + bfrag[n]), 0.f);
      *(unsigned short*)(myH + byte) = (unsigned short)(pk2(hv, hv) & 0xFFFFu);
    }
  }

  // ---- layer 2: [16 rows] x [32 o], K = 64 ----
  f32x4 acc2[2];
  acc2[0] = f32x4{0.f, 0.f, 0.f, 0.f};
  acc2[1] = f32x4{0.f, 0.f, 0.f, 0.f};
  #pragma unroll
  for (int k2 = 0; k2 < 2; ++k2) {
    const int kb = (k2 * 32 + lkg * 8) * 2;
    const int ax = (lrow * 128 + kb) ^ ((lrow & 7) << 4);
    bf8_t a2 = lds_load16(myH, ax);
    #pragma unroll
    for (int n2 = 0; n2 < 2; ++n2)
      acc2[n2] = __builtin_amdgcn_mfma_f32_16x16x32_bf16(a2, wl[n2][k2], acc2[n2], 0, 0, 0);
  }

  // epilogue 2: out = relu(acc + bl), scattered row stores
  const size_t obase = (size_t)side * N_ROWS * ODIM;
  #pragma unroll
  for (int n2 = 0; n2 < 2; ++n2) {
    int col  = n2 * 16 + lrow;
    float bb = (n2 == 0) ? blv0 : blv1;
    #pragma unroll
    for (int q = 0; q < 4; ++q) {
      int idx = idxQ[q];
      if (idx >= 0)
        out[obase + (size_t)idx * ODIM + col] = fmaxf(acc2[n2][q] + bb, 0.f);
    }
  }
}

extern "C" void kernel_launch(void* const* d_in, const int* in_sizes, int n_in,
                              void* d_out, int out_size, void* d_ws, size_t ws_size,
                              hipStream_t stream) {
  const float* user = (const float*)d_in[0];
  const float* item = (const float*)d_in[1];
  const int*   r    = (const int*)d_in[2];
  const float* c    = (const float*)d_in[3];
  const float* Wu   = (const float*)d_in[4];
  const float* bu   = (const float*)d_in[5];
  const float* Wv   = (const float*)d_in[6];
  const float* bv   = (const float*)d_in[7];
  const float* Wl   = (const float*)d_in[8];
  const float* bl   = (const float*)d_in[9];
  float* out = (float*)d_out;

  int* bucket = (int*)d_ws;          // NB ints
  int* cnt    = bucket + NB;         // KREL
  int* cursor = cnt + KREL;          // KREL
  int* aoff   = cursor + KREL;       // KREL+1

  hipMemsetAsync(bucket, 0xFF, (size_t)NB * sizeof(int), stream);
  hipMemsetAsync(cnt, 0, KREL * sizeof(int), stream);

  const int nthr = 256;
  hist_kernel<<<(N_ROWS + nthr - 1) / nthr, nthr, 0, stream>>>(r, cnt);
  offs_kernel<<<1, 1, 0, stream>>>(cnt, aoff, cursor);
  scat_kernel<<<(N_ROWS + nthr - 1) / nthr, nthr, 0, stream>>>(r, bucket, cursor);
  gcn_main<<<2 * NTILES, 256, 0, stream>>>(user, item, c, Wu, bu, Wv, bv, Wl, bl,
                                           bucket, aoff, out);
}

// Round 4
// 135.571 us; speedup vs baseline: 1.9026x; 1.2077x over previous
//
#include <hip/hip_runtime.h>
#include <hip/hip_bf16.h>

#define N_ROWS 300000
#define FIN    128
#define HDIM   64
#define ODIM   32
#define KREL   5
#define BR     64
#define NTILES ((N_ROWS + BR - 1) / BR + KREL)   // 4693
#define NB     (NTILES * BR)
#define TPB    8
#define NBLK_SIDE ((NTILES + TPB - 1) / TPB)     // 587

typedef __attribute__((ext_vector_type(8))) short bf8_t;   // 8 bf16 = 4 VGPR
typedef __attribute__((ext_vector_type(4))) float f32x4;
typedef __attribute__((ext_vector_type(4))) unsigned int u32x4;

static __device__ __forceinline__ unsigned pk2(float lo, float hi) {
  __hip_bfloat162 h = __float22bfloat162_rn(make_float2(lo, hi));
  return *reinterpret_cast<unsigned*>(&h);
}

static __device__ __forceinline__ bf8_t cvt8(float4 a, float4 b) {
  u32x4 u;
  u.x = pk2(a.x, a.y);
  u.y = pk2(a.z, a.w);
  u.z = pk2(b.x, b.y);
  u.w = pk2(b.z, b.w);
  return __builtin_bit_cast(bf8_t, u);
}

static __device__ __forceinline__ void stbf4_pk(void* base, int byte, float4 v) {
  unsigned long long p = (unsigned long long)pk2(v.x, v.y)
                       | ((unsigned long long)pk2(v.z, v.w) << 32);
  *(unsigned long long*)((char*)base + byte) = p;
}

static __device__ __forceinline__ bf8_t lds_load16(const void* base, int byte) {
  return *(const bf8_t*)((const char*)base + byte);
}

// ---------------- bucketing ----------------

__global__ void hist_kernel(const int* __restrict__ r, int* __restrict__ cnt) {
  __shared__ int lc[KREL];
  int tid = threadIdx.x;
  if (tid < KREL) lc[tid] = 0;
  __syncthreads();
  int i = blockIdx.x * blockDim.x + tid;
  if (i < N_ROWS) atomicAdd(&lc[r[i]], 1);
  __syncthreads();
  if (tid < KREL && lc[tid]) atomicAdd(&cnt[tid], lc[tid]);
}

__global__ void offs_kernel(const int* __restrict__ cnt, int* __restrict__ aoff,
                            int* __restrict__ cursor) {
  int off = 0;
  for (int k = 0; k < KREL; ++k) {
    aoff[k] = off;
    cursor[k] = off;
    off += ((cnt[k] + BR - 1) / BR) * BR;
  }
  aoff[KREL] = off;
}

__global__ void scat_kernel(const int* __restrict__ r, const float* __restrict__ c,
                            int* __restrict__ bucket, float* __restrict__ cbv,
                            int* __restrict__ cursor) {
  __shared__ int lc[KREL];
  __shared__ int base[KREL];
  int tid = threadIdx.x;
  if (tid < KREL) lc[tid] = 0;
  __syncthreads();
  int i = blockIdx.x * blockDim.x + tid;
  int k = 0, lr = 0;
  float cv = 0.f;
  if (i < N_ROWS) { k = r[i]; lr = atomicAdd(&lc[k], 1); cv = c[i]; }
  __syncthreads();
  if (tid < KREL) base[tid] = lc[tid] ? atomicAdd(&cursor[tid], lc[tid]) : 0;
  __syncthreads();
  if (i < N_ROWS) {
    int pos = base[k] + lr;
    bucket[pos] = i;
    cbv[pos]    = cv;
  }
}

// ---------------- main fused kernel ----------------
// One block = one side x a chunk of TPB 64-row tiles. 256 threads = 4 waves.
// Double-buffered X (bf16), W staged per block, one barrier per tile.

__global__ __launch_bounds__(256, 3) void gcn_main(
    const float* __restrict__ user, const float* __restrict__ item,
    const float* __restrict__ Wu, const float* __restrict__ bu,
    const float* __restrict__ Wv, const float* __restrict__ bv,
    const float* __restrict__ Wl, const float* __restrict__ bl,
    const int* __restrict__ bucket, const float* __restrict__ cbv,
    const int* __restrict__ aoff, float* __restrict__ out)
{
  __shared__ __align__(16) unsigned short sW[HDIM * FIN];      // 16 KB
  __shared__ __align__(16) unsigned short sX[2][BR * FIN];     // 2 x 16 KB

  const int tid   = threadIdx.x;
  const int side  = blockIdx.x & 1;            // 0: item->u_out, 1: user->v_out
  const int chunk = blockIdx.x >> 1;
  const int t_begin = chunk * TPB;
  const int t_end   = (t_begin + TPB < NTILES) ? t_begin + TPB : NTILES;

  const float* X  = side ? user : item;
  const float* Wk = side ? Wv : Wu;
  const float* bk = side ? bv : bu;

  const int a1 = aoff[1], a2 = aoff[2], a3 = aoff[3], a4 = aoff[4];

  const int lane  = tid & 63;
  const int wid   = tid >> 6;        // wave 0..3, owns rows [wid*16, wid*16+16)
  const int lrow  = lane & 15;
  const int lkg   = lane >> 4;
  const int srow0 = tid >> 5;        // staging: row base (0..7)
  const int sc4   = tid & 31;        // staging: float4 column

  // layer-2 weights + bias in registers
  bf8_t wl[2][2];
  #pragma unroll
  for (int n2 = 0; n2 < 2; ++n2)
    #pragma unroll
    for (int k2 = 0; k2 < 2; ++k2) {
      const float* p = Wl + (size_t)(n2 * 16 + lrow) * HDIM + k2 * 32 + lkg * 8;
      wl[n2][k2] = cvt8(*(const float4*)p, *(const float4*)(p + 4));
    }
  const float blv0 = bl[lrow];
  const float blv1 = bl[16 + lrow];

  int rel = ((t_begin * BR) >= a1) + ((t_begin * BR) >= a2)
          + ((t_begin * BR) >= a3) + ((t_begin * BR) >= a4);

  // stage relation weights -> bf16 LDS, XOR-swizzled (row stride 256 B)
  {
    const float4* w4 = (const float4*)(Wk + (size_t)rel * HDIM * FIN);
    #pragma unroll
    for (int it = 0; it < 8; ++it) {
      int f4  = it * 256 + tid;
      int row = f4 >> 5;
      int c4  = f4 & 31;
      int byte = (row * 256 + c4 * 8) ^ ((row & 7) << 4);
      stbf4_pk(sW, byte, w4[f4]);
    }
  }
  float bfrag[4];
  #pragma unroll
  for (int n = 0; n < 4; ++n) bfrag[n] = bk[rel * HDIM + n * 16 + lrow];

  // two-tile-ahead row-index prefetch (registers)
  int idxA[8], idxB[8];
  {
    const int tB = (t_begin + 1 < NTILES) ? t_begin + 1 : NTILES - 1;
    #pragma unroll
    for (int it = 0; it < 8; ++it) {
      idxA[it] = bucket[t_begin * BR + it * 8 + srow0];
      idxB[it] = bucket[tB * BR + it * 8 + srow0];
    }
  }

  // stage first X tile into sX[0]
  #pragma unroll
  for (int it = 0; it < 8; ++it) {
    int idx  = idxA[it] < 0 ? 0 : idxA[it];
    float4 a = *(const float4*)(X + (size_t)idx * FIN + sc4 * 4);
    int row  = it * 8 + srow0;
    int byte = (row * 256 + sc4 * 8) ^ ((row & 7) << 4);
    stbf4_pk(sX[0], byte, a);
  }
  __syncthreads();

  for (int t = t_begin; t < t_end; ++t) {
    const int pb = (t - t_begin) & 1;
    unsigned short* buf  = sX[pb];
    unsigned short* nbuf = sX[pb ^ 1];
    const int tile0 = t * BR;

    // prefetch bucket indices for t+2 (latency covered by 2 tiles)
    int idxC[8];
    {
      const int tC = (t + 2 < NTILES) ? t + 2 : NTILES - 1;
      #pragma unroll
      for (int it = 0; it < 8; ++it)
        idxC[it] = bucket[tC * BR + it * 8 + srow0];
    }

    // issue-early: stage tile t+1 into the spare buffer (overlaps with MFMA below)
    if (t + 1 < t_end) {
      #pragma unroll
      for (int it = 0; it < 8; ++it) {
        int idx  = idxB[it] < 0 ? 0 : idxB[it];
        float4 a = *(const float4*)(X + (size_t)idx * FIN + sc4 * 4);
        int row  = it * 8 + srow0;
        int byte = (row * 256 + sc4 * 8) ^ ((row & 7) << 4);
        stbf4_pk(nbuf, byte, a);
      }
    }

    // epilogue inputs: coalesced vector loads (no dependent gather)
    const int erow = tile0 + wid * 16 + lkg * 4;
    int4   idxQ4 = *(const int4*)(bucket + erow);
    float4 cQ4   = *(const float4*)(cbv + erow);
    int   idxQ[4] = {idxQ4.x, idxQ4.y, idxQ4.z, idxQ4.w};
    float cQ[4]   = {cQ4.x, cQ4.y, cQ4.z, cQ4.w};

    // ---- layer 1: [64 rows] x [64 h], K = 128 ----
    f32x4 acc[4];
    #pragma unroll
    for (int n = 0; n < 4; ++n) acc[n] = f32x4{0.f, 0.f, 0.f, 0.f};

    const int arow = wid * 16 + lrow;
    const int axor = (arow & 7) << 4;
    #pragma unroll
    for (int kc = 0; kc < 4; ++kc) {
      const int kb = (kc * 32 + lkg * 8) * 2;
      bf8_t au = lds_load16(buf, (arow * 256 + kb) ^ axor);
      #pragma unroll
      for (int n = 0; n < 4; ++n) {
        int brow = n * 16 + lrow;
        int bx   = (brow * 256 + kb) ^ ((brow & 7) << 4);
        acc[n] = __builtin_amdgcn_mfma_f32_16x16x32_bf16(au, lds_load16(sW, bx), acc[n], 0, 0, 0);
      }
    }

    // epilogue 1: H = relu(c*(acc+b)) -> bf16 into THIS WAVE'S own 4 KB of buf
    // (wave-private rows; same-wave LDS ordering, no barrier needed)
    char* myH = (char*)buf + wid * 4096;
    #pragma unroll
    for (int n = 0; n < 4; ++n) {
      int hcol = n * 16 + lrow;
      #pragma unroll
      for (int q = 0; q < 4; ++q) {
        int rr   = lkg * 4 + q;      // local row 0..15
        int byte = (rr * 128 + hcol * 2) ^ ((rr & 7) << 4);
        float hv = fmaxf(cQ[q] * (acc[n][q] + bfrag[n]), 0.f);
        *(unsigned short*)(myH + byte) = (unsigned short)(pk2(hv, hv) & 0xFFFFu);
      }
    }

    // ---- layer 2: [16 rows] x [32 o], K = 64 ----
    f32x4 acc2[2];
    acc2[0] = f32x4{0.f, 0.f, 0.f, 0.f};
    acc2[1] = f32x4{0.f, 0.f, 0.f, 0.f};
    #pragma unroll
    for (int k2 = 0; k2 < 2; ++k2) {
      const int kb = (k2 * 32 + lkg * 8) * 2;
      const int ax = (lrow * 128 + kb) ^ ((lrow & 7) << 4);
      bf8_t a2 = lds_load16(myH, ax);
      #pragma unroll
      for (int n2 = 0; n2 < 2; ++n2)
        acc2[n2] = __builtin_amdgcn_mfma_f32_16x16x32_bf16(a2, wl[n2][k2], acc2[n2], 0, 0, 0);
    }

    // epilogue 2: out = relu(acc2 + bl), scattered row stores
    const size_t obase = (size_t)side * N_ROWS * ODIM;
    #pragma unroll
    for (int n2 = 0; n2 < 2; ++n2) {
      int col  = n2 * 16 + lrow;
      float bb = (n2 == 0) ? blv0 : blv1;
      #pragma unroll
      for (int q = 0; q < 4; ++q) {
        int idx = idxQ[q];
        if (idx >= 0)
          out[obase + (size_t)idx * ODIM + col] = fmaxf(acc2[n2][q] + bb, 0.f);
      }
    }

    // rotate index prefetch
    #pragma unroll
    for (int it = 0; it < 8; ++it) idxB[it] = idxC[it];

    __syncthreads();   // nbuf fully staged; all waves done with buf

    // relation boundary within the chunk (rare: <=4 per side globally)
    if (t + 1 < t_end) {
      int tn0  = (t + 1) * BR;
      int relN = (tn0 >= a1) + (tn0 >= a2) + (tn0 >= a3) + (tn0 >= a4);
      if (relN != rel) {
        rel = relN;
        const float4* w4 = (const float4*)(Wk + (size_t)rel * HDIM * FIN);
        #pragma unroll
        for (int it = 0; it < 8; ++it) {
          int f4  = it * 256 + tid;
          int row = f4 >> 5;
          int c4  = f4 & 31;
          int byte = (row * 256 + c4 * 8) ^ ((row & 7) << 4);
          stbf4_pk(sW, byte, w4[f4]);
        }
        #pragma unroll
        for (int n = 0; n < 4; ++n) bfrag[n] = bk[rel * HDIM + n * 16 + lrow];
        __syncthreads();
      }
    }
  }
}

extern "C" void kernel_launch(void* const* d_in, const int* in_sizes, int n_in,
                              void* d_out, int out_size, void* d_ws, size_t ws_size,
                              hipStream_t stream) {
  const float* user = (const float*)d_in[0];
  const float* item = (const float*)d_in[1];
  const int*   r    = (const int*)d_in[2];
  const float* c    = (const float*)d_in[3];
  const float* Wu   = (const float*)d_in[4];
  const float* bu   = (const float*)d_in[5];
  const float* Wv   = (const float*)d_in[6];
  const float* bv   = (const float*)d_in[7];
  const float* Wl   = (const float*)d_in[8];
  const float* bl   = (const float*)d_in[9];
  float* out = (float*)d_out;

  int*   bucket = (int*)d_ws;            // NB ints
  float* cbv    = (float*)(bucket + NB); // NB floats
  int*   cnt    = (int*)(cbv + NB);      // KREL
  int*   cursor = cnt + KREL;            // KREL
  int*   aoff   = cursor + KREL;         // KREL+1

  hipMemsetAsync(bucket, 0xFF, (size_t)NB * sizeof(int), stream);
  hipMemsetAsync(cbv, 0, (size_t)NB * sizeof(float), stream);
  hipMemsetAsync(cnt, 0, KREL * sizeof(int), stream);

  const int nthr = 256;
  hist_kernel<<<(N_ROWS + nthr - 1) / nthr, nthr, 0, stream>>>(r, cnt);
  offs_kernel<<<1, 1, 0, stream>>>(cnt, aoff, cursor);
  scat_kernel<<<(N_ROWS + nthr - 1) / nthr, nthr, 0, stream>>>(r, c, bucket, cbv, cursor);
  gcn_main<<<2 * NBLK_SIDE, 256, 0, stream>>>(user, item, Wu, bu, Wv, bv, Wl, bl,
                                              bucket, cbv, aoff, out);
}